// Round 3
// baseline (376.818 us; speedup 1.0000x reference)
//
#include <hip/hip_runtime.h>
#include <stdint.h>

#define N 8192
#define K 64
#define TILE 128
#define JT 8            // j-tiles per block: each block streams a 128 x 1024 strip of W
#define NSTEP (4 * JT)  // flat (jt, mt) step count

typedef __attribute__((ext_vector_type(8))) short bf16x8;
typedef __attribute__((ext_vector_type(4))) float floatx4;
typedef __attribute__((ext_vector_type(4))) unsigned short ushort4v;

// ---- prep: Y fp32 -> bf16 (RNE), sq[i] = ||y_i||^2, zero the output ----
__global__ __launch_bounds__(256) void prep_kernel(const float* __restrict__ Y,
                                                   unsigned short* __restrict__ Ybf,
                                                   float* __restrict__ sq,
                                                   float* __restrict__ out) {
    if (blockIdx.x == 0 && threadIdx.x == 0) out[0] = 0.0f;
    const int t = blockIdx.x * 256 + threadIdx.x;
    floatx4 v = *reinterpret_cast<const floatx4*>(Y + (size_t)t * 4);
    ushort4v o;
    #pragma unroll
    for (int e = 0; e < 4; ++e) {
        uint32_t bits = __float_as_uint(v[e]);
        uint32_t rnd  = bits + 0x7FFF + ((bits >> 16) & 1);   // round-to-nearest-even
        o[e] = (unsigned short)(rnd >> 16);
    }
    *reinterpret_cast<ushort4v*>(Ybf + (size_t)t * 4) = o;
    float s = v[0]*v[0] + v[1]*v[1] + v[2]*v[2] + v[3]*v[3];
    #pragma unroll
    for (int m = 8; m >= 1; m >>= 1) s += __shfl_xor(s, m, 64);
    if ((threadIdx.x & 15) == 0) sq[t >> 4] = s;
}

// ---- main: streaming strip kernel. 512 blocks (2/CU resident), each owns a
// 128x1024 strip of W. W streams through a rolling 4-deep register buffer of
// per-wave groups (4 x float4 / lane); refill for group s+4 issues as group s
// is consumed -> ~3 KB of W in flight per wave continuously. Accumulator is
// one mt-row (4 x floatx4 = 16 VGPR), epilogued immediately. ----
__global__ __launch_bounds__(256, 2) void loss_kernel(const float* __restrict__ W,
                                                      const unsigned short* __restrict__ Ybf,
                                                      const float* __restrict__ sq,
                                                      float* __restrict__ out) {
    __shared__ float wsum[4];

    const int i0   = (blockIdx.x >> 3) * TILE;        // 64 i-strips
    const int j0   = (blockIdx.x & 7) * (TILE * JT);  // 8 j-strips of 1024
    const int tid  = threadIdx.x;
    const int wv   = tid >> 6;
    const int lane = tid & 63;
    const int qRow = (wv >> 1) * 64;          // i-quadrant base within 128-tile
    const int qCol = (wv & 1) * 64;           // j-quadrant base within 128-tile
    const int laneM = lane & 15;
    const int kq    = lane >> 4;

    // --- i-side fragments + sqi (fixed for the whole strip) ---
    bf16x8 afrag[2][4];
    float  sqi[4];
    #pragma unroll
    for (int mt = 0; mt < 4; ++mt) {
        const int row = i0 + qRow + mt * 16 + laneM;
        afrag[0][mt] = *reinterpret_cast<const bf16x8*>(Ybf + (size_t)row * K + kq * 8);
        afrag[1][mt] = *reinterpret_cast<const bf16x8*>(Ybf + (size_t)row * K + 32 + kq * 8);
        sqi[mt] = sq[row];
    }

    // --- j-side ping-pong buffers, preload tile 0 ---
    bf16x8  bfr[2][2][4];     // [buf][ks][nt]
    floatx4 sqjb[2][4];       // [buf][nt]
    #pragma unroll
    for (int nt = 0; nt < 4; ++nt) {
        const int row = j0 + qCol + nt * 16 + laneM;
        bfr[0][0][nt] = *reinterpret_cast<const bf16x8*>(Ybf + (size_t)row * K + kq * 8);
        bfr[0][1][nt] = *reinterpret_cast<const bf16x8*>(Ybf + (size_t)row * K + 32 + kq * 8);
        sqjb[0][nt]   = *reinterpret_cast<const floatx4*>(sq + j0 + qCol + nt * 16 + kq * 4);
    }

    // --- W stream base for this lane; group (jt,mt) nt-element lives at
    //     wl + mt*16*N + jt*128 + nt*16 (all compile-time after unroll) ---
    const float* wl = W + (size_t)(i0 + qRow + laneM) * N + (j0 + qCol + kq * 4);

    // preload W groups 0..3 (tile 0, mt = 0..3)
    floatx4 wfb[4][4];
    #pragma unroll
    for (int g = 0; g < 4; ++g)
        #pragma unroll
        for (int nt = 0; nt < 4; ++nt)
            wfb[g][nt] = *reinterpret_cast<const floatx4*>(wl + (size_t)g * 16 * N + nt * 16);

    float p0 = 0.f, p1 = 0.f, p2 = 0.f, p3 = 0.f;

    #pragma unroll
    for (int s = 0; s < NSTEP; ++s) {
        const int mt  = s & 3;
        const int jt  = s >> 2;
        const int buf = jt & 1;

        // tile-boundary: prefetch next tile's bfrag + sqj into the other buffer
        if (mt == 0 && jt + 1 < JT) {
            #pragma unroll
            for (int nt = 0; nt < 4; ++nt) {
                const int row = j0 + (jt + 1) * TILE + qCol + nt * 16 + laneM;
                bfr[buf ^ 1][0][nt] = *reinterpret_cast<const bf16x8*>(Ybf + (size_t)row * K + kq * 8);
                bfr[buf ^ 1][1][nt] = *reinterpret_cast<const bf16x8*>(Ybf + (size_t)row * K + 32 + kq * 8);
                sqjb[buf ^ 1][nt]   = *reinterpret_cast<const floatx4*>(sq + j0 + (jt + 1) * TILE + qCol + nt * 16 + kq * 4);
            }
        }

        // MFMA for (jt, mt): operand-swapped so col(lane&15)=i, row-quad=j
        floatx4 accv[4];
        #pragma unroll
        for (int nt = 0; nt < 4; ++nt) accv[nt] = (floatx4){0.f, 0.f, 0.f, 0.f};
        #pragma unroll
        for (int ks = 0; ks < 2; ++ks)
            #pragma unroll
            for (int nt = 0; nt < 4; ++nt)
                accv[nt] = __builtin_amdgcn_mfma_f32_16x16x32_bf16(bfr[buf][ks][nt], afrag[ks][mt], accv[nt], 0, 0, 0);

        // epilogue: d = max(sq_i + sq_j - 2g, 0); partial += W*d
        const float si = sqi[mt];
        #pragma unroll
        for (int nt = 0; nt < 4; ++nt) {
            const floatx4 g  = accv[nt];
            const floatx4 w4 = wfb[s & 3][nt];
            const floatx4 sj = sqjb[buf][nt];
            p0 = fmaf(w4[0], fmaxf(si + sj[0] - 2.0f * g[0], 0.f), p0);
            p1 = fmaf(w4[1], fmaxf(si + sj[1] - 2.0f * g[1], 0.f), p1);
            p2 = fmaf(w4[2], fmaxf(si + sj[2] - 2.0f * g[2], 0.f), p2);
            p3 = fmaf(w4[3], fmaxf(si + sj[3] - 2.0f * g[3], 0.f), p3);
        }

        // refill the just-consumed slot with group s+4 (same mt, tile jt+1)
        if (s + 4 < NSTEP) {
            #pragma unroll
            for (int nt = 0; nt < 4; ++nt)
                wfb[s & 3][nt] = *reinterpret_cast<const floatx4*>(
                    wl + (size_t)mt * 16 * N + (jt + 1) * TILE + nt * 16);
        }
    }

    float partial = (p0 + p1) + (p2 + p3);
    #pragma unroll
    for (int m = 32; m >= 1; m >>= 1) partial += __shfl_xor(partial, m, 64);
    if (lane == 0) wsum[wv] = partial;
    __syncthreads();
    if (tid == 0) {
        float tot = (wsum[0] + wsum[1]) + (wsum[2] + wsum[3]);
        atomicAdd(out, tot * (1.0f / (2.0f * (float)N)));
    }
}

extern "C" void kernel_launch(void* const* d_in, const int* in_sizes, int n_in,
                              void* d_out, int out_size, void* d_ws, size_t ws_size,
                              hipStream_t stream) {
    const float* W = (const float*)d_in[0];
    const float* Y = (const float*)d_in[1];
    float* out = (float*)d_out;

    unsigned short* Ybf = (unsigned short*)d_ws;                  // N*K*2 = 1 MiB
    float* sq = (float*)((char*)d_ws + (size_t)N * K * 2);        // N*4   = 32 KiB

    prep_kernel<<<(N * K / 4) / 256, 256, 0, stream>>>(Y, Ybf, sq, out);
    loss_kernel<<<(N / TILE) * (N / (TILE * JT)), 256, 0, stream>>>(W, Ybf, sq, out);
}

// Round 4
// 365.296 us; speedup vs baseline: 1.0315x; 1.0315x over previous
//
#include <hip/hip_runtime.h>
#include <stdint.h>

#define N 8192
#define K 64
#define JT_PER 8      // j-tiles (32 cols each) per wave strip -> 256-col block strip

typedef __attribute__((ext_vector_type(8))) short bf16x8;
typedef __attribute__((ext_vector_type(4))) float floatx4;
typedef __attribute__((ext_vector_type(4))) unsigned short ushort4v;

// ---- prep: Y fp32 -> bf16 (RNE), sq[i] = ||y_i||^2, zero the output ----
__global__ __launch_bounds__(256) void prep_kernel(const float* __restrict__ Y,
                                                   unsigned short* __restrict__ Ybf,
                                                   float* __restrict__ sq,
                                                   float* __restrict__ out) {
    if (blockIdx.x == 0 && threadIdx.x == 0) out[0] = 0.0f;
    const int t = blockIdx.x * 256 + threadIdx.x;
    floatx4 v = *reinterpret_cast<const floatx4*>(Y + (size_t)t * 4);
    ushort4v o;
    #pragma unroll
    for (int e = 0; e < 4; ++e) {
        uint32_t bits = __float_as_uint(v[e]);
        uint32_t rnd  = bits + 0x7FFF + ((bits >> 16) & 1);   // round-to-nearest-even
        o[e] = (unsigned short)(rnd >> 16);
    }
    *reinterpret_cast<ushort4v*>(Ybf + (size_t)t * 4) = o;
    float s = v[0]*v[0] + v[1]*v[1] + v[2]*v[2] + v[3]*v[3];
    #pragma unroll
    for (int m = 8; m >= 1; m >>= 1) s += __shfl_xor(s, m, 64);
    if ((threadIdx.x & 15) == 0) sq[t >> 4] = s;
}

// ---- main: high-occupancy streaming. Per wave: 32i x 32j tile, strip of 8
// j-tiles. Small footprint (~115 VGPR) -> 4 waves/SIMD = 16 waves/CU. W flows
// through a depth-1 double buffer (4 KB/wave continuously in flight; 64 KB/CU).
// Issue order per iter keeps the W stream outstanding across every vmcnt wait:
// [bfrag+sqj this iter][W next iter][MFMA (waits bfrag)][epilogue (waits W_cur)].
__global__ __launch_bounds__(256, 4) void loss_kernel(const float* __restrict__ W,
                                                      const unsigned short* __restrict__ Ybf,
                                                      const float* __restrict__ sq,
                                                      float* __restrict__ out) {
    __shared__ float wsum[4];

    const int bid  = blockIdx.x;
    const int i0   = (bid >> 5) * 128;          // 64 i-groups
    const int j0   = (bid & 31) * 256;          // 32 j-strips
    const int tid  = threadIdx.x;
    const int wv   = tid >> 6;
    const int lane = tid & 63;
    const int laneM = lane & 15;
    const int kq    = lane >> 4;
    const int iw    = i0 + wv * 32;             // this wave's 32 i-rows

    // --- i-side fragments + sqi (fixed for the strip) ---
    bf16x8 a[2][2];        // [mt][ks]
    float  sqi[2];
    #pragma unroll
    for (int mt = 0; mt < 2; ++mt) {
        const int row = iw + mt * 16 + laneM;
        a[mt][0] = *reinterpret_cast<const bf16x8*>(Ybf + (size_t)row * K + kq * 8);
        a[mt][1] = *reinterpret_cast<const bf16x8*>(Ybf + (size_t)row * K + 32 + kq * 8);
        sqi[mt]  = sq[row];
    }

    // --- W lane base pointers (row = iw + mt*16 + laneM, col base = j0 + kq*4) ---
    const float* wp0 = W + (size_t)(iw + laneM) * N + j0 + kq * 4;
    const float* wp1 = wp0 + (size_t)16 * N;

    // preload W for jt=0
    floatx4 wbuf[2][2][2];  // [pp][mt][nt]
    #pragma unroll
    for (int nt = 0; nt < 2; ++nt) {
        wbuf[0][0][nt] = *reinterpret_cast<const floatx4*>(wp0 + nt * 16);
        wbuf[0][1][nt] = *reinterpret_cast<const floatx4*>(wp1 + nt * 16);
    }

    float p0 = 0.f, p1 = 0.f, p2 = 0.f, p3 = 0.f;

    #pragma unroll
    for (int jt = 0; jt < JT_PER; ++jt) {
        const int pp = jt & 1;
        const int jb = j0 + jt * 32;

        // (1) j-side fragments + sqj for THIS iter (L2-hot; issued first so the
        //     MFMA wait on them leaves the W stream outstanding)
        bf16x8  b[2][2];   // [nt][ks]
        floatx4 sjq[2];
        #pragma unroll
        for (int nt = 0; nt < 2; ++nt) {
            const int rowj = jb + nt * 16 + laneM;
            b[nt][0] = *reinterpret_cast<const bf16x8*>(Ybf + (size_t)rowj * K + kq * 8);
            b[nt][1] = *reinterpret_cast<const bf16x8*>(Ybf + (size_t)rowj * K + 32 + kq * 8);
            sjq[nt]  = *reinterpret_cast<const floatx4*>(sq + jb + nt * 16 + kq * 4);
        }

        // (2) W prefetch for NEXT iter into the other buffer
        if (jt + 1 < JT_PER) {
            #pragma unroll
            for (int nt = 0; nt < 2; ++nt) {
                wbuf[pp ^ 1][0][nt] = *reinterpret_cast<const floatx4*>(wp0 + (jt + 1) * 32 + nt * 16);
                wbuf[pp ^ 1][1][nt] = *reinterpret_cast<const floatx4*>(wp1 + (jt + 1) * 32 + nt * 16);
            }
        }

        // (3) MFMA, swapped operands: col(lane&15)=i-local, row-quad=j-local
        floatx4 acc[2][2];
        #pragma unroll
        for (int mt = 0; mt < 2; ++mt)
            #pragma unroll
            for (int nt = 0; nt < 2; ++nt) acc[mt][nt] = (floatx4){0.f, 0.f, 0.f, 0.f};
        #pragma unroll
        for (int ks = 0; ks < 2; ++ks)
            #pragma unroll
            for (int mt = 0; mt < 2; ++mt)
                #pragma unroll
                for (int nt = 0; nt < 2; ++nt)
                    acc[mt][nt] = __builtin_amdgcn_mfma_f32_16x16x32_bf16(b[nt][ks], a[mt][ks], acc[mt][nt], 0, 0, 0);

        // (4) epilogue: d = max(sq_i + sq_j - 2g, 0); partial += W*d
        #pragma unroll
        for (int mt = 0; mt < 2; ++mt) {
            const float si = sqi[mt];
            #pragma unroll
            for (int nt = 0; nt < 2; ++nt) {
                const floatx4 g  = acc[mt][nt];
                const floatx4 w4 = wbuf[pp][mt][nt];
                const floatx4 sj = sjq[nt];
                p0 = fmaf(w4[0], fmaxf(si + sj[0] - 2.0f * g[0], 0.f), p0);
                p1 = fmaf(w4[1], fmaxf(si + sj[1] - 2.0f * g[1], 0.f), p1);
                p2 = fmaf(w4[2], fmaxf(si + sj[2] - 2.0f * g[2], 0.f), p2);
                p3 = fmaf(w4[3], fmaxf(si + sj[3] - 2.0f * g[3], 0.f), p3);
            }
        }
    }

    float partial = (p0 + p1) + (p2 + p3);
    #pragma unroll
    for (int m = 32; m >= 1; m >>= 1) partial += __shfl_xor(partial, m, 64);
    if (lane == 0) wsum[wv] = partial;
    __syncthreads();
    if (tid == 0) {
        float tot = (wsum[0] + wsum[1]) + (wsum[2] + wsum[3]);
        atomicAdd(out, tot * (1.0f / (2.0f * (float)N)));
    }
}

extern "C" void kernel_launch(void* const* d_in, const int* in_sizes, int n_in,
                              void* d_out, int out_size, void* d_ws, size_t ws_size,
                              hipStream_t stream) {
    const float* W = (const float*)d_in[0];
    const float* Y = (const float*)d_in[1];
    float* out = (float*)d_out;

    unsigned short* Ybf = (unsigned short*)d_ws;                  // N*K*2 = 1 MiB
    float* sq = (float*)((char*)d_ws + (size_t)N * K * 2);        // N*4   = 32 KiB

    prep_kernel<<<(N * K / 4) / 256, 256, 0, stream>>>(Y, Ybf, sq, out);
    // grid: 64 i-groups x 32 j-strips = 2048 blocks (2 generations of 4/CU)
    loss_kernel<<<64 * 32, 256, 0, stream>>>(W, Ybf, sq, out);
}

// Round 5
// 362.584 us; speedup vs baseline: 1.0393x; 1.0075x over previous
//
#include <hip/hip_runtime.h>
#include <stdint.h>

#define N 8192
#define K 64
#define JT_PER 8      // j-tiles (32 cols) per strip -> block strip = 128i x 256j

typedef __attribute__((ext_vector_type(8))) short bf16x8;
typedef __attribute__((ext_vector_type(4))) float floatx4;
typedef __attribute__((ext_vector_type(4))) unsigned short ushort4v;

// ---- prep: Y fp32 -> bf16 (RNE), sq[i] = ||y_i||^2, zero the output ----
__global__ __launch_bounds__(256) void prep_kernel(const float* __restrict__ Y,
                                                   unsigned short* __restrict__ Ybf,
                                                   float* __restrict__ sq,
                                                   float* __restrict__ out) {
    if (blockIdx.x == 0 && threadIdx.x == 0) out[0] = 0.0f;
    const int t = blockIdx.x * 256 + threadIdx.x;
    floatx4 v = *reinterpret_cast<const floatx4*>(Y + (size_t)t * 4);
    ushort4v o;
    #pragma unroll
    for (int e = 0; e < 4; ++e) {
        uint32_t bits = __float_as_uint(v[e]);
        uint32_t rnd  = bits + 0x7FFF + ((bits >> 16) & 1);   // round-to-nearest-even
        o[e] = (unsigned short)(rnd >> 16);
    }
    *reinterpret_cast<ushort4v*>(Ybf + (size_t)t * 4) = o;
    float s = v[0]*v[0] + v[1]*v[1] + v[2]*v[2] + v[3]*v[3];
    #pragma unroll
    for (int m = 8; m >= 1; m >>= 1) s += __shfl_xor(s, m, 64);
    if ((threadIdx.x & 15) == 0) sq[t >> 4] = s;
}

// ---- main: W is the ONLY global load in the K-loop. j-side Ybf fragments
// pre-staged in LDS in fragment order (lane*16 contiguous -> conflict-free
// ds_read_b128); sq[j] in LDS (broadcast reads). W streams at prefetch depth 2
// (3 rotating buffers, 8 KB/wave outstanding; 128 KB/CU at 16 waves/CU). The
// per-iter vmcnt wait is only for W issued 2 iterations ago. ----
__global__ __launch_bounds__(256, 4) void loss_kernel(const float* __restrict__ W,
                                                      const unsigned short* __restrict__ Ybf,
                                                      const float* __restrict__ sq,
                                                      float* __restrict__ out) {
    // fragment block fb = (jt*2+nt)*2+ks, 64 lanes x 16 B each
    __shared__ __align__(16) bf16x8 lB[JT_PER * 2 * 2 * 64];   // 32 KB
    __shared__ __align__(16) float  lsq[256];                  // 1 KB
    __shared__ float wsum[4];

    const int bid  = blockIdx.x;
    const int i0   = (bid >> 5) * 128;          // 64 i-groups
    const int j0   = (bid & 31) * 256;          // 32 j-strips
    const int tid  = threadIdx.x;
    const int wv   = tid >> 6;
    const int lane = tid & 63;
    const int laneM = lane & 15;
    const int kq    = lane >> 4;
    const int iw    = i0 + wv * 32;             // this wave's 32 i-rows

    // --- stage j-side Ybf (256 rows) into LDS in fragment order ---
    #pragma unroll
    for (int it = 0; it < 8; ++it) {
        const int u  = it * 256 + tid;
        const int l  = u & 63;
        const int fb = u >> 6;
        const int jt = fb >> 2;
        const int nt = (fb >> 1) & 1;
        const int ks = fb & 1;
        lB[u] = *reinterpret_cast<const bf16x8*>(
            Ybf + (size_t)(j0 + jt * 32 + nt * 16 + (l & 15)) * K + ks * 32 + (l >> 4) * 8);
    }
    if (tid < 64)
        *reinterpret_cast<floatx4*>(&lsq[tid * 4]) = *reinterpret_cast<const floatx4*>(sq + j0 + tid * 4);

    // --- i-side fragments + sqi (global, pre-loop, L2-hot) ---
    bf16x8 a[2][2];        // [mt][ks]
    float  sqi[2];
    #pragma unroll
    for (int mt = 0; mt < 2; ++mt) {
        const int row = iw + mt * 16 + laneM;
        a[mt][0] = *reinterpret_cast<const bf16x8*>(Ybf + (size_t)row * K + kq * 8);
        a[mt][1] = *reinterpret_cast<const bf16x8*>(Ybf + (size_t)row * K + 32 + kq * 8);
        sqi[mt]  = sq[row];
    }

    // --- W lane base pointers (row = iw + mt*16 + laneM, col base = j0 + kq*4) ---
    const float* wp0 = W + (size_t)(iw + laneM) * N + j0 + kq * 4;
    const float* wp1 = wp0 + (size_t)16 * N;

    // preload W for jt=0,1 (depth-2 pipeline, 3 rotating buffers)
    floatx4 wbuf[3][2][2];  // [buf][mt][nt]
    #pragma unroll
    for (int g = 0; g < 2; ++g)
        #pragma unroll
        for (int nt = 0; nt < 2; ++nt) {
            wbuf[g][0][nt] = *reinterpret_cast<const floatx4*>(wp0 + g * 32 + nt * 16);
            wbuf[g][1][nt] = *reinterpret_cast<const floatx4*>(wp1 + g * 32 + nt * 16);
        }

    __syncthreads();   // LDS staging visible; W preloads stay outstanding

    float p0 = 0.f, p1 = 0.f, p2 = 0.f, p3 = 0.f;

    #pragma unroll
    for (int jt = 0; jt < JT_PER; ++jt) {
        const int buf = jt % 3;

        // (1) j-side fragments + sqj from LDS (lgkmcnt only)
        bf16x8  b[2][2];   // [nt][ks]
        floatx4 sjq[2];
        #pragma unroll
        for (int nt = 0; nt < 2; ++nt) {
            b[nt][0] = lB[((jt * 2 + nt) * 2 + 0) * 64 + lane];
            b[nt][1] = lB[((jt * 2 + nt) * 2 + 1) * 64 + lane];
            sjq[nt]  = *reinterpret_cast<const floatx4*>(&lsq[jt * 32 + nt * 16 + kq * 4]);
        }

        // (2) W prefetch for jt+2 into the rotating buffer
        if (jt + 2 < JT_PER) {
            const int pb = (jt + 2) % 3;
            #pragma unroll
            for (int nt = 0; nt < 2; ++nt) {
                wbuf[pb][0][nt] = *reinterpret_cast<const floatx4*>(wp0 + (jt + 2) * 32 + nt * 16);
                wbuf[pb][1][nt] = *reinterpret_cast<const floatx4*>(wp1 + (jt + 2) * 32 + nt * 16);
            }
        }

        // (3) MFMA, swapped operands: col(lane&15)=i-local, row-quad=j-local
        floatx4 acc[2][2];
        #pragma unroll
        for (int mt = 0; mt < 2; ++mt)
            #pragma unroll
            for (int nt = 0; nt < 2; ++nt) acc[mt][nt] = (floatx4){0.f, 0.f, 0.f, 0.f};
        #pragma unroll
        for (int ks = 0; ks < 2; ++ks)
            #pragma unroll
            for (int mt = 0; mt < 2; ++mt)
                #pragma unroll
                for (int nt = 0; nt < 2; ++nt)
                    acc[mt][nt] = __builtin_amdgcn_mfma_f32_16x16x32_bf16(b[nt][ks], a[mt][ks], acc[mt][nt], 0, 0, 0);

        // (4) epilogue: d = max(sq_i + sq_j - 2g, 0); partial += W*d
        //     waits vmcnt for W_jt (issued 2 iterations ago; W_{jt+1},W_{jt+2} stay in flight)
        #pragma unroll
        for (int mt = 0; mt < 2; ++mt) {
            const float si = sqi[mt];
            #pragma unroll
            for (int nt = 0; nt < 2; ++nt) {
                const floatx4 g  = acc[mt][nt];
                const floatx4 w4 = wbuf[buf][mt][nt];
                const floatx4 sj = sjq[nt];
                p0 = fmaf(w4[0], fmaxf(si + sj[0] - 2.0f * g[0], 0.f), p0);
                p1 = fmaf(w4[1], fmaxf(si + sj[1] - 2.0f * g[1], 0.f), p1);
                p2 = fmaf(w4[2], fmaxf(si + sj[2] - 2.0f * g[2], 0.f), p2);
                p3 = fmaf(w4[3], fmaxf(si + sj[3] - 2.0f * g[3], 0.f), p3);
            }
        }
    }

    float partial = (p0 + p1) + (p2 + p3);
    #pragma unroll
    for (int m = 32; m >= 1; m >>= 1) partial += __shfl_xor(partial, m, 64);
    if (lane == 0) wsum[wv] = partial;
    __syncthreads();
    if (tid == 0) {
        float tot = (wsum[0] + wsum[1]) + (wsum[2] + wsum[3]);
        atomicAdd(out, tot * (1.0f / (2.0f * (float)N)));
    }
}

extern "C" void kernel_launch(void* const* d_in, const int* in_sizes, int n_in,
                              void* d_out, int out_size, void* d_ws, size_t ws_size,
                              hipStream_t stream) {
    const float* W = (const float*)d_in[0];
    const float* Y = (const float*)d_in[1];
    float* out = (float*)d_out;

    unsigned short* Ybf = (unsigned short*)d_ws;                  // N*K*2 = 1 MiB
    float* sq = (float*)((char*)d_ws + (size_t)N * K * 2);        // N*4   = 32 KiB

    prep_kernel<<<(N * K / 4) / 256, 256, 0, stream>>>(Y, Ybf, sq, out);
    // 64 i-groups x 32 j-strips = 2048 blocks (4 blocks/CU resident x 2 generations)
    loss_kernel<<<64 * 32, 256, 0, stream>>>(W, Ybf, sq, out);
}